// Round 12
// baseline (295.810 us; speedup 1.0000x reference)
//
#include <hip/hip_runtime.h>
#include <hip/hip_bf16.h>

#define N_NODES 50000
#define N_EDGES 1600000
#define NGRAPH  16
#define HID     128

#define RPB   128                           // rows per bucket
#define NB    ((N_NODES + RPB - 1) / RPB)   // 391 buckets
#define NBLK  256                           // partition blocks
#define EPB   ((N_EDGES + NBLK - 1) / NBLK) // 6250 edges per partition block

typedef unsigned int uint32;
typedef unsigned short ushort;
typedef unsigned char uchar;
typedef __attribute__((ext_vector_type(8))) short bf16x8;
typedef __attribute__((ext_vector_type(4))) float f32x4;
typedef __attribute__((ext_vector_type(2))) float f32x2;

// bf16 round-to-nearest-even helpers
__device__ __forceinline__ uint32 bf16r(float f) {
    uint32 b = __float_as_uint(f);
    return (b + 0x7fffu + ((b >> 16) & 1u)) >> 16;
}
__device__ __forceinline__ uint32 pack_bf16(float lo, float hi) {
    return bf16r(lo) | (bf16r(hi) << 16);
}
__device__ __forceinline__ float bf_lo(uint32 u) { return __uint_as_float(u << 16); }
__device__ __forceinline__ float bf_hi(uint32 u) { return __uint_as_float(u & 0xffff0000u); }

// ------- init (fused): zero accumulators+counters, graph bounds, weight pack, v3 -------
__global__ __launch_bounds__(256) void k_init(float* __restrict__ zp, int zn,
                                              const int* __restrict__ batch,
                                              int* __restrict__ gstart,
                                              const float* __restrict__ W2,
                                              const float* __restrict__ W7,
                                              const float* __restrict__ W3,
                                              const float* __restrict__ W4,
                                              ushort* __restrict__ wpack,
                                              float* __restrict__ v3) {
    int idx = blockIdx.x * 256 + threadIdx.x;
    if (idx < zn) zp[idx] = 0.f;
    if (idx <= NGRAPH) {
        int lo = 0, hi = N_NODES;
        while (lo < hi) {
            int mid = (lo + hi) >> 1;
            if (batch[mid] < idx) lo = mid + 1; else hi = mid;
        }
        gstart[idx] = lo;
    }
    if (idx < 4 * 16384) {
        int m = idx >> 14, f = idx & 16383;
        int j = f & 7, lane = (f >> 3) & 63, kk = (f >> 9) & 3, t = (f >> 11) & 7;
        int hp = t * 16 + (lane & 15);
        int k  = kk * 32 + ((lane >> 4) & 3) * 8 + j;
        const float* src = (m < 3) ? (W2 + m * HID * HID) : W7;
        wpack[idx] = (ushort)bf16r(src[hp * HID + k]);
    }
    if (idx < 3 * HID) {
        int l = idx / HID, hp = idx % HID;
        float acc = 0.f;
        for (int h = 0; h < HID; h++)
            acc += W3[l * HID * HID + hp * HID + h] * fmaxf(W4[l * HID + h], 0.f);
        v3[idx] = acc;
    }
}

// ---------------- P1: per-(bucket,block) histogram ----------------
__global__ __launch_bounds__(1024) void k_p1_hist(const int* __restrict__ row,
                                                  int* __restrict__ blkhist) {
    __shared__ int hist[NB];
    int tid = threadIdx.x, blk = blockIdx.x;
    for (int i = tid; i < NB; i += 1024) hist[i] = 0;
    __syncthreads();
    int s = blk * EPB, e = s + EPB; if (e > N_EDGES) e = N_EDGES;
    for (int i = s + tid; i < e; i += 1024)
        atomicAdd(&hist[row[i] >> 7], 1);
    __syncthreads();
    for (int i = tid; i < NB; i += 1024)
        blkhist[i * NBLK + blk] = hist[i];
}

// ------- P2 (fused): per-bucket scan over NBLK counts; last block scans bucket totals -------
__global__ __launch_bounds__(NBLK) void k_p2(int* __restrict__ blkhist,
                                             int* __restrict__ btot,
                                             int* __restrict__ bbase,
                                             int* __restrict__ done) {
    __shared__ int sums[NBLK];
    __shared__ int lastflag;
    int t = threadIdx.x, b = blockIdx.x;
    int v = blkhist[b * NBLK + t];
    sums[t] = v;
    __syncthreads();
    for (int d = 1; d < NBLK; d <<= 1) {
        int u = (t >= d) ? sums[t - d] : 0;
        __syncthreads();
        sums[t] += u;
        __syncthreads();
    }
    blkhist[b * NBLK + t] = sums[t] - v;     // local exclusive
    if (t == NBLK - 1) btot[b] = sums[t];    // bucket total
    if (t == 0) {
        __threadfence();
        int old = atomicAdd(done, 1);
        lastflag = (old == NB - 1);
    }
    __syncthreads();
    if (lastflag) {
        int i0 = 2 * t, i1 = 2 * t + 1;
        int v0 = (i0 < NB) ? atomicAdd(&btot[i0], 0) : 0;
        int v1 = (i1 < NB) ? atomicAdd(&btot[i1], 0) : 0;
        int sum = v0 + v1;
        sums[t] = sum;
        __syncthreads();
        for (int d = 1; d < NBLK; d <<= 1) {
            int u = (t >= d) ? sums[t - d] : 0;
            __syncthreads();
            sums[t] += u;
            __syncthreads();
        }
        int excl = sums[t] - sum;
        if (i0 < NB) bbase[i0] = excl;
        if (i1 < NB) bbase[i1] = excl + v0;
        if (t == NBLK - 1) bbase[NB] = sums[t]; // == E
    }
}

// ------- P3: scatter int2{rowlocal:8|col:16, ea} into bucket runs (LDS cursors) -------
__global__ __launch_bounds__(1024) void k_p3_part(const int* __restrict__ row,
                                                  const int* __restrict__ col,
                                                  const float* __restrict__ ea,
                                                  const int* __restrict__ blkhist,
                                                  const int* __restrict__ bbase,
                                                  int2* __restrict__ pea) {
    __shared__ int cur[NB];
    int tid = threadIdx.x, blk = blockIdx.x;
    for (int i = tid; i < NB; i += 1024)
        cur[i] = bbase[i] + blkhist[i * NBLK + blk];
    __syncthreads();
    int s = blk * EPB, e = s + EPB; if (e > N_EDGES) e = N_EDGES;
    for (int i = s + tid; i < e; i += 1024) {
        int r = row[i], c = col[i];
        float a = ea[i];
        int slot = atomicAdd(&cur[r >> 7], 1);
        pea[slot] = make_int2(((r & (RPB - 1)) << 16) | c, __float_as_int(a));
    }
}

// ------- P4a: per-bucket counts + ea_sum + local scan -> offs, pxe -------
__global__ __launch_bounds__(512) void k_p4a(const int2* __restrict__ pea,
                                             const int* __restrict__ bbase,
                                             const float* __restrict__ x,
                                             int* __restrict__ offs,
                                             float* __restrict__ ea_sum,
                                             float2* __restrict__ pxe) {
    __shared__ int   cnt[RPB];
    __shared__ float eas[RPB];
    __shared__ int   scan_s[RPB];
    int tid = threadIdx.x, b = blockIdx.x;
    if (tid < RPB) { cnt[tid] = 0; eas[tid] = 0.f; }
    __syncthreads();
    int s = bbase[b], e = bbase[b + 1];
    for (int i = s + tid; i < e; i += 512) {
        int2 p = pea[i];
        int lr = ((uint32)p.x) >> 16;
        atomicAdd(&cnt[lr], 1);
        atomicAdd(&eas[lr], __int_as_float(p.y));
    }
    __syncthreads();
    if (tid < RPB) scan_s[tid] = cnt[tid];
    __syncthreads();
    for (int d = 1; d < RPB; d <<= 1) {
        int v = 0;
        if (tid < RPB && tid >= d) v = scan_s[tid - d];
        __syncthreads();
        if (tid < RPB) scan_s[tid] += v;
        __syncthreads();
    }
    int nbase = b * RPB;
    if (tid < RPB) {
        int excl = scan_s[tid] - cnt[tid];
        int n = nbase + tid;
        if (n < N_NODES) {
            offs[n] = s + excl;
            ea_sum[n] = eas[tid];
            pxe[n] = make_float2(x[n], eas[tid]);
        }
    }
    if (b == NB - 1 && tid == 0) offs[N_NODES] = e;
}

// ------- P4b: scatter csr + CSR-ordered payload pxec[slot] = pxe[col] -------
__global__ __launch_bounds__(512) void k_p4b(const int2* __restrict__ pea,
                                             const int* __restrict__ bbase,
                                             const int* __restrict__ offs,
                                             const float2* __restrict__ pxe,
                                             int* __restrict__ csr,
                                             float2* __restrict__ pxec) {
    __shared__ int cur[RPB];
    int tid = threadIdx.x, b = blockIdx.x;
    int nbase = b * RPB;
    if (tid < RPB) cur[tid] = (nbase + tid < N_NODES) ? offs[nbase + tid] : 0;
    __syncthreads();
    int s = bbase[b], e = bbase[b + 1];
    for (int i = s + tid; i < e; i += 512) {
        int2 p = pea[i];
        int c = p.x & 0xFFFF;
        int slot = atomicAdd(&cur[((uint32)p.x) >> 16], 1);
        csr[slot] = c;
        pxec[slot] = pxe[c];   // 400 KB table, L2-resident
    }
}

// ------- hop-1 gather by recompute, streaming CSR-ordered payload (no indirection) -------
__global__ __launch_bounds__(256) void k_gather1(const float2* __restrict__ pxec,
                                                 const int* __restrict__ offs,
                                                 const float* __restrict__ w1,
                                                 const float* __restrict__ v3,
                                                 uint32* __restrict__ agg) {
    int node = (blockIdx.x * 256 + threadIdx.x) >> 6;
    int lane = threadIdx.x & 63;
    if (node >= N_NODES) return;
    f32x2 w1v = {w1[2 * lane], w1[2 * lane + 1]};
    f32x2 v3v = {v3[2 * lane], v3[2 * lane + 1]};
    const f32x2 zero = {0.f, 0.f};
    int s = offs[node], e = offs[node + 1];
    f32x2 acc[4] = {zero, zero, zero, zero};
    int j = s;
    for (; j + 8 <= e; j += 8) {
        float2 p[8];
#pragma unroll
        for (int u = 0; u < 8; u++) p[u] = pxec[j + u];   // broadcast, contiguous
#pragma unroll
        for (int u = 0; u < 8; u++) {
            f32x2 px = {p[u].x, p[u].x};
            f32x2 pe = {p[u].y, p[u].y};
            f32x2 r = __builtin_elementwise_fma(px, w1v, pe * v3v);
            acc[u & 3] += __builtin_elementwise_max(r, zero);
        }
    }
    for (; j < e; j++) {
        float2 p = pxec[j];
        f32x2 px = {p.x, p.x};
        f32x2 pe = {p.y, p.y};
        f32x2 r = __builtin_elementwise_fma(px, w1v, pe * v3v);
        acc[0] += __builtin_elementwise_max(r, zero);
    }
    f32x2 rs = (acc[0] + acc[1]) + (acc[2] + acc[3]);
    agg[(size_t)node * 64 + lane] = pack_bf16(rs.x, rs.y);
}

// ------- hop-2 gather over fp8 emb rows (128 B): coalesced csr + shfl; 8-deep MLP -------
// (round-8 proven form: ushort/lane, E visits, 8 loads in flight, occupancy ~68%)
__global__ __launch_bounds__(256) void k_gather(const uchar* __restrict__ emb8,
                                                const int* __restrict__ offs,
                                                const int* __restrict__ csr,
                                                uint32* __restrict__ agg) {
    int node = (blockIdx.x * 256 + threadIdx.x) >> 6;
    int lane = threadIdx.x & 63;
    if (node >= N_NODES) return;
    int s = offs[node], e = offs[node + 1];
    float ax[8] = {0.f}, ay[8] = {0.f};
    for (int base = s; base < e; base += 64) {
        int idx = base + lane;
        int cv = (idx < e) ? csr[idx] : 0;     // one coalesced load per 64 edges
        int cnt = e - base; if (cnt > 64) cnt = 64;
        int j = 0;
        for (; j + 8 <= cnt; j += 8) {
            int h16[8];
#pragma unroll
            for (int u = 0; u < 8; u++) {
                int c = __shfl(cv, j + u);
                h16[u] = *(const ushort*)(emb8 + (size_t)c * 128 + 2 * lane);
            }
#pragma unroll
            for (int u = 0; u < 8; u++) {
                f32x2 d = __builtin_amdgcn_cvt_pk_f32_fp8(h16[u], false);
                ax[u] += d.x; ay[u] += d.y;
            }
        }
        for (; j < cnt; j++) {
            int c = __shfl(cv, j);
            int h = *(const ushort*)(emb8 + (size_t)c * 128 + 2 * lane);
            f32x2 d = __builtin_amdgcn_cvt_pk_f32_fp8(h, false);
            ax[0] += d.x; ay[0] += d.y;
        }
    }
    float rx = (((ax[0] + ax[1]) + (ax[2] + ax[3])) + ((ax[4] + ax[5]) + (ax[6] + ax[7]))) * 64.f;
    float ry = (((ay[0] + ay[1]) + (ay[2] + ay[3])) + ((ay[4] + ay[5]) + (ay[6] + ay[7]))) * 64.f;
    agg[(size_t)node * 64 + lane] = pack_bf16(rx, ry);
}

#define LROW 136  // padded LDS row, bf16 elems

// ------- MFMA GEMM hop: emb = relu(agg @ W2T + x*w1 + ea*v3) -------
// !LAST: emit fp8 emb (scale 2^-6, row 128 B). LAST: emit bf16 emb + fused W7-head.
template <bool LAST>
__global__ __launch_bounds__(256) void k_gemm(const uint32* __restrict__ agg,   // bf16 [N][64u32]
                                              const ushort* __restrict__ w2p,   // B-frag packed
                                              const float* __restrict__ w1l,
                                              const float* __restrict__ v3l,
                                              const float* __restrict__ x,
                                              const float* __restrict__ ea_sum,
                                              uint32* __restrict__ embOut,      // bf16 (LAST)
                                              uchar* __restrict__ emb8Out,      // fp8 (!LAST)
                                              const ushort* __restrict__ w7p,
                                              const float* __restrict__ W5,
                                              float* __restrict__ outp) {
    __shared__ ushort tile[64 * LROW]; // 17408 B
    int tid = threadIdx.x;
    int tbase = blockIdx.x * 64;
    {
        const uint2* src = (const uint2*)(agg + (size_t)tbase * 64);
        int vn = N_NODES - tbase; if (vn > 64) vn = 64;
        int lim = vn * 32;
        for (int i = tid; i < 64 * 32; i += 256) {
            uint2 u = (i < lim) ? src[i] : make_uint2(0u, 0u);
            int r = i >> 5, c4 = (i & 31) * 4;
            *(uint2*)&tile[r * LROW + c4] = u;
        }
    }
    __syncthreads();
    int wv = tid >> 6, lane = tid & 63;
    int n0 = lane & 15, quad = lane >> 4;
    int arow = wv * 16 + n0;
    bf16x8 a0 = *(const bf16x8*)&tile[arow * LROW + 0 * 32 + quad * 8];
    bf16x8 a1 = *(const bf16x8*)&tile[arow * LROW + 1 * 32 + quad * 8];
    bf16x8 a2 = *(const bf16x8*)&tile[arow * LROW + 2 * 32 + quad * 8];
    bf16x8 a3 = *(const bf16x8*)&tile[arow * LROW + 3 * 32 + quad * 8];
    const bf16x8* wb = (const bf16x8*)w2p;
    f32x4 acc[8];
#pragma unroll
    for (int t = 0; t < 8; t++) {
        f32x4 c = {0.f, 0.f, 0.f, 0.f};
        c = __builtin_amdgcn_mfma_f32_16x16x32_bf16(a0, wb[(t * 4 + 0) * 64 + lane], c, 0, 0, 0);
        c = __builtin_amdgcn_mfma_f32_16x16x32_bf16(a1, wb[(t * 4 + 1) * 64 + lane], c, 0, 0, 0);
        c = __builtin_amdgcn_mfma_f32_16x16x32_bf16(a2, wb[(t * 4 + 2) * 64 + lane], c, 0, 0, 0);
        c = __builtin_amdgcn_mfma_f32_16x16x32_bf16(a3, wb[(t * 4 + 3) * 64 + lane], c, 0, 0, 0);
        acc[t] = c;
    }
    float xs[4], es[4];
#pragma unroll
    for (int r = 0; r < 4; r++) {
        int n = tbase + wv * 16 + quad * 4 + r;
        xs[r] = (n < N_NODES) ? x[n] : 0.f;
        es[r] = (n < N_NODES) ? ea_sum[n] : 0.f;
    }
    if (!LAST) {
        // epilogue: fp8 output, scale 2^-6 (exact pow2; rescaled x64 in k_gather)
        uchar* stile = (uchar*)tile;   // rows stride 136 B; wave-private rows
#pragma unroll
        for (int t = 0; t < 8; t++) {
            int hp = t * 16 + n0;
            float w1v = w1l[hp], v3v = v3l[hp];
#pragma unroll
            for (int r = 0; r < 4; r++) {
                float v = fmaxf(acc[t][r] + xs[r] * w1v + es[r] * v3v, 0.f) * 0.015625f;
                int enc = __builtin_amdgcn_cvt_pk_fp8_f32(v, v, 0, false);
                stile[(wv * 16 + quad * 4 + r) * 136 + hp] = (uchar)(enc & 0xff);
            }
        }
        __syncthreads();
        int vn = N_NODES - tbase; if (vn > 64) vn = 64;
        for (int i = tid; i < 64 * 32; i += 256) {
            int r = i >> 5, c4 = (i & 31) * 4;
            if (r < vn) {
                uint32 u = *(const uint32*)&stile[r * 136 + c4];
                *(uint32*)(emb8Out + (size_t)(tbase + r) * 128 + c4) = u;
            }
        }
    } else {
        // epilogue: bf16 output back through LDS + fused W7 head
#pragma unroll
        for (int t = 0; t < 8; t++) {
            int hp = t * 16 + n0;
            float w1v = w1l[hp], v3v = v3l[hp];
#pragma unroll
            for (int r = 0; r < 4; r++) {
                float v = fmaxf(acc[t][r] + xs[r] * w1v + es[r] * v3v, 0.f);
                tile[(wv * 16 + quad * 4 + r) * LROW + hp] = (ushort)bf16r(v);
            }
        }
        __syncthreads();
        {
            int vn = N_NODES - tbase; if (vn > 64) vn = 64;
            for (int i = tid; i < 64 * 32; i += 256) {
                int r = i >> 5, c4 = (i & 31) * 4;
                if (r < vn) {
                    uint2 u = *(const uint2*)&tile[r * LROW + c4];
                    *(uint2*)(embOut + (size_t)(tbase + r) * 64 + (size_t)(i & 31) * 2) = u;
                }
            }
        }
        bf16x8 b0 = *(const bf16x8*)&tile[arow * LROW + 0 * 32 + quad * 8];
        bf16x8 b1 = *(const bf16x8*)&tile[arow * LROW + 1 * 32 + quad * 8];
        bf16x8 b2 = *(const bf16x8*)&tile[arow * LROW + 2 * 32 + quad * 8];
        bf16x8 b3 = *(const bf16x8*)&tile[arow * LROW + 3 * 32 + quad * 8];
        const bf16x8* w7 = (const bf16x8*)w7p;
        float p[4] = {0.f, 0.f, 0.f, 0.f};
#pragma unroll
        for (int t = 0; t < 8; t++) {
            f32x4 c = {0.f, 0.f, 0.f, 0.f};
            c = __builtin_amdgcn_mfma_f32_16x16x32_bf16(b0, w7[(t * 4 + 0) * 64 + lane], c, 0, 0, 0);
            c = __builtin_amdgcn_mfma_f32_16x16x32_bf16(b1, w7[(t * 4 + 1) * 64 + lane], c, 0, 0, 0);
            c = __builtin_amdgcn_mfma_f32_16x16x32_bf16(b2, w7[(t * 4 + 2) * 64 + lane], c, 0, 0, 0);
            c = __builtin_amdgcn_mfma_f32_16x16x32_bf16(b3, w7[(t * 4 + 3) * 64 + lane], c, 0, 0, 0);
            float w5v = W5[128 + t * 16 + n0];
#pragma unroll
            for (int r = 0; r < 4; r++) p[r] += fmaxf(c[r], 0.f) * w5v;
        }
#pragma unroll
        for (int r = 0; r < 4; r++) {
            float v = p[r];
            v += __shfl_xor(v, 1);
            v += __shfl_xor(v, 2);
            v += __shfl_xor(v, 4);
            v += __shfl_xor(v, 8);
            int n = tbase + wv * 16 + quad * 4 + r;
            if (n0 == 0 && n < N_NODES) outp[n] = v;
        }
    }
}

// ------- pooling (fused s_g): 256 blocks; last block computes s_g = relu(pooled@W6T).W5[:128] -------
__global__ __launch_bounds__(256) void k_pool2(const uint32* __restrict__ emb,
                                               const int* __restrict__ gstart,
                                               float* __restrict__ pooled,
                                               int* __restrict__ done,
                                               const float* __restrict__ W6,
                                               const float* __restrict__ W5,
                                               float* __restrict__ s_g) {
    __shared__ float2 red[4][64];
    __shared__ int lastflag;
    int bid = blockIdx.x;
    int g = bid >> 4, chunk = bid & 15;
    int gs = gstart[g], ge = gstart[g + 1];
    int len = ge - gs;
    int cs = gs + (int)(((long long)len * chunk) >> 4);
    int ce = gs + (int)(((long long)len * (chunk + 1)) >> 4);
    int sub = threadIdx.x >> 6, lane = threadIdx.x & 63;
    float ax = 0.f, ay = 0.f;
    for (int n = cs + sub; n < ce; n += 4) {
        uint32 u = emb[(size_t)n * 64 + lane];
        ax += bf_lo(u); ay += bf_hi(u);
    }
    red[sub][lane] = make_float2(ax, ay);
    __syncthreads();
    if (sub == 0) {
        float2 r0 = red[0][lane], r1 = red[1][lane], r2 = red[2][lane], r3 = red[3][lane];
        atomicAdd(&pooled[g * HID + 2 * lane],     (r0.x + r1.x) + (r2.x + r3.x));
        atomicAdd(&pooled[g * HID + 2 * lane + 1], (r0.y + r1.y) + (r2.y + r3.y));
    }
    if (threadIdx.x == 0) {
        __threadfence();
        int old = atomicAdd(done, 1);
        lastflag = (old == (int)gridDim.x - 1);
    }
    __syncthreads();
    if (lastflag) {
        __shared__ float pool_s[NGRAPH * HID]; // 8 KB
        __shared__ float red2[NGRAPH * HID];   // 8 KB
        int tid = threadIdx.x;
        for (int i = tid; i < NGRAPH * HID; i += 256)
            pool_s[i] = atomicAdd(&pooled[i], 0.f);   // coherent read
        __syncthreads();
        if (tid < HID) {
            int hp = tid;
            float acc[NGRAPH];
#pragma unroll
            for (int gg = 0; gg < NGRAPH; gg++) acc[gg] = 0.f;
            for (int h = 0; h < HID; h++) {
                float wv = W6[hp * HID + h];
#pragma unroll
                for (int gg = 0; gg < NGRAPH; gg++)
                    acc[gg] += pool_s[gg * HID + h] * wv;
            }
            float w5v = W5[hp];
#pragma unroll
            for (int gg = 0; gg < NGRAPH; gg++)
                red2[gg * HID + hp] = fmaxf(acc[gg], 0.f) * w5v;
        }
        __syncthreads();
        if (tid < NGRAPH) {
            float s = 0.f;
            for (int h = 0; h < HID; h++) s += red2[tid * HID + h];
            s_g[tid] = s;
        }
    }
}

// ---------------- final add: out[n] += s_g[batch[n]] + b5 ----------------
__global__ __launch_bounds__(256) void k_addsg(float* __restrict__ out,
                                               const int* __restrict__ batch,
                                               const float* __restrict__ s_g,
                                               const float* __restrict__ b5) {
    int n = blockIdx.x * 256 + threadIdx.x;
    if (n < N_NODES) out[n] += s_g[batch[n]] + b5[0];
}

extern "C" void kernel_launch(void* const* d_in, const int* in_sizes, int n_in,
                              void* d_out, int out_size, void* d_ws, size_t ws_size,
                              hipStream_t stream) {
    (void)in_sizes; (void)n_in; (void)out_size; (void)ws_size;
    const float* x    = (const float*)d_in[0];
    const int*   ei   = (const int*)d_in[1];   // [2,E] flat: row then col
    const float* ea   = (const float*)d_in[2];
    const int*   bat  = (const int*)d_in[3];
    const float* W1   = (const float*)d_in[4]; // [3,128,1]
    const float* W2   = (const float*)d_in[5]; // [3,128,128]
    const float* W3   = (const float*)d_in[6];
    const float* W4   = (const float*)d_in[7]; // [3,128,1]
    const float* W5   = (const float*)d_in[8]; // [1,256]
    const float* b5   = (const float*)d_in[9];
    const float* W6   = (const float*)d_in[10];
    const float* W7   = (const float*)d_in[11];
    float* out = (float*)d_out;

    const int* row = ei;
    const int* col = ei + N_EDGES;

    // workspace layout (4B elems)
    float* wsf = (float*)d_ws;
    int*   wsi = (int*)d_ws;
    size_t o = 0;
    float* pooled = wsf + o; o += NGRAPH * HID;     // zeroed (atomic targets)
    float* s_g    = wsf + o; o += NGRAPH;           // zeroed
    int*   done_p2   = wsi + o; o += 1;             // zeroed arrival counters
    int*   done_pool = wsi + o; o += 1;
    size_t ztot = o;
    int*   offs   = wsi + o; o += N_NODES + 1;
    float* ea_sum = wsf + o; o += N_NODES;
    int*   gstart = wsi + o; o += NGRAPH + 1;
    int*   btot   = wsi + o; o += NB;
    int*   bbase  = wsi + o; o += NB + 1;
    float* v3     = wsf + o; o += 3 * HID;
    int*   blkh   = wsi + o; o += NB * NBLK;
    o = (o + 1) & ~(size_t)1;
    float2* pxe   = (float2*)(wsi + o); o += 2 * (size_t)N_NODES;
    o = (o + 3) & ~(size_t)3;
    ushort* wpack = (ushort*)(wsi + o); o += 4 * 16384 / 2;
    int*    csr   = wsi + o; o += N_EDGES;
    o = (o + 1) & ~(size_t)1;
    int2*   pea   = (int2*)(wsi + o); o += 2 * (size_t)N_EDGES;
    float2* pxec  = (float2*)(wsi + o); o += 2 * (size_t)N_EDGES;
    o = (o + 1) & ~(size_t)1;
    uint32* embA  = (uint32*)(wsi + o); o += (size_t)N_NODES * 64;  // bf16 [N][128]
    uchar*  emb8  = (uchar*)(wsi + o);  o += (size_t)N_NODES * 32;  // fp8 [N][128]
    uint32* aggB  = (uint32*)(wsi + o); o += (size_t)N_NODES * 64;  // bf16 [N][128]

    const ushort* w2p1 = wpack + 1 * 16384;
    const ushort* w2p2 = wpack + 2 * 16384;
    const ushort* w7p  = wpack + 3 * 16384;

    // 0) init: zero accumulators/counters + graph bounds + weight pack + v3 (fused)
    k_init<<<256, 256, 0, stream>>>((float*)d_ws, (int)ztot, bat, gstart,
                                    W2, W7, W3, W4, (ushort*)wpack, v3);
    // 1) atomic-free CSR build + CSR-ordered hop-1 payload
    k_p1_hist<<<NBLK, 1024, 0, stream>>>(row, blkh);
    k_p2<<<NB, NBLK, 0, stream>>>(blkh, btot, bbase, done_p2);
    k_p3_part<<<NBLK, 1024, 0, stream>>>(row, col, ea, blkh, bbase, pea);
    k_p4a<<<NB, 512, 0, stream>>>(pea, bbase, x, offs, ea_sum, pxe);
    k_p4b<<<NB, 512, 0, stream>>>(pea, bbase, offs, pxe, csr, pxec);
    // 2) hop 1: streaming recompute-gather -> aggB ; MFMA gemm -> fp8 emb
    k_gather1<<<(N_NODES * 64 + 255) / 256, 256, 0, stream>>>(pxec, offs, W1, v3, aggB);
    k_gemm<false><<<(N_NODES + 63) / 64, 256, 0, stream>>>(
        aggB, w2p1, W1 + 1 * HID, v3 + 1 * HID, x, ea_sum, nullptr, emb8, nullptr, nullptr, nullptr);
    // 3) hop 2: fp8 gather -> aggB ; MFMA gemm + W7 head -> embA, out partial
    k_gather<<<(N_NODES * 64 + 255) / 256, 256, 0, stream>>>(emb8, offs, csr, aggB);
    k_gemm<true><<<(N_NODES + 63) / 64, 256, 0, stream>>>(
        aggB, w2p2, W1 + 2 * HID, v3 + 2 * HID, x, ea_sum, embA, nullptr, w7p, W5, out);
    // 4) graph pooling + fused s_g (last-block)
    k_pool2<<<NGRAPH * 16, 256, 0, stream>>>(embA, gstart, pooled, done_pool, W6, W5, s_g);
    // 5) add graph term + bias
    k_addsg<<<(N_NODES + 255) / 256, 256, 0, stream>>>(out, bat, s_g, b5);
}

// Round 13
// 283.330 us; speedup vs baseline: 1.0440x; 1.0440x over previous
//
#include <hip/hip_runtime.h>
#include <hip/hip_bf16.h>

#define N_NODES 50000
#define N_EDGES 1600000
#define NGRAPH  16
#define HID     128

#define RPB   128                           // rows per bucket
#define NB    ((N_NODES + RPB - 1) / RPB)   // 391 buckets
#define NBLK  256                           // partition blocks
#define EPB   ((N_EDGES + NBLK - 1) / NBLK) // 6250 edges per partition block

typedef unsigned int uint32;
typedef unsigned short ushort;
typedef unsigned char uchar;
typedef __attribute__((ext_vector_type(8))) short bf16x8;
typedef __attribute__((ext_vector_type(4))) float f32x4;
typedef __attribute__((ext_vector_type(2))) float f32x2;

// bf16 round-to-nearest-even helpers
__device__ __forceinline__ uint32 bf16r(float f) {
    uint32 b = __float_as_uint(f);
    return (b + 0x7fffu + ((b >> 16) & 1u)) >> 16;
}
__device__ __forceinline__ uint32 pack_bf16(float lo, float hi) {
    return bf16r(lo) | (bf16r(hi) << 16);
}
__device__ __forceinline__ float bf_lo(uint32 u) { return __uint_as_float(u << 16); }
__device__ __forceinline__ float bf_hi(uint32 u) { return __uint_as_float(u & 0xffff0000u); }

// ---------------- init: zero accumulators + graph boundaries ----------------
__global__ __launch_bounds__(256) void k_init(float* p, int n,
                                              const int* __restrict__ batch,
                                              int* __restrict__ gstart) {
    int i = blockIdx.x * 256 + threadIdx.x;
    if (i < n) p[i] = 0.f;
    if (i <= NGRAPH) {
        int lo = 0, hi = N_NODES;
        while (lo < hi) {
            int mid = (lo + hi) >> 1;
            if (batch[mid] < i) lo = mid + 1; else hi = mid;
        }
        gstart[i] = lo;
    }
}

// ---------------- P1: per-(bucket,block) histogram ----------------
__global__ __launch_bounds__(1024) void k_p1_hist(const int* __restrict__ row,
                                                  int* __restrict__ blkhist) {
    __shared__ int hist[NB];
    int tid = threadIdx.x, blk = blockIdx.x;
    for (int i = tid; i < NB; i += 1024) hist[i] = 0;
    __syncthreads();
    int s = blk * EPB, e = s + EPB; if (e > N_EDGES) e = N_EDGES;
    for (int i = s + tid; i < e; i += 1024)
        atomicAdd(&hist[row[i] >> 7], 1);
    __syncthreads();
    for (int i = tid; i < NB; i += 1024)
        blkhist[i * NBLK + blk] = hist[i];
}

// ------- P2a: per-bucket exclusive scan over its NBLK per-block counts -------
__global__ __launch_bounds__(NBLK) void k_p2a(int* __restrict__ blkhist,
                                              int* __restrict__ btot) {
    __shared__ int sums[NBLK];
    int t = threadIdx.x, b = blockIdx.x;
    int v = blkhist[b * NBLK + t];
    sums[t] = v;
    __syncthreads();
    for (int d = 1; d < NBLK; d <<= 1) {
        int u = (t >= d) ? sums[t - d] : 0;
        __syncthreads();
        sums[t] += u;
        __syncthreads();
    }
    blkhist[b * NBLK + t] = sums[t] - v;     // local exclusive
    if (t == NBLK - 1) btot[b] = sums[t];    // bucket total
}

// ------- P2b: scan bucket totals -> bucket bases -------
__global__ __launch_bounds__(512) void k_p2b(const int* __restrict__ btot,
                                             int* __restrict__ bbase) {
    __shared__ int sums[512];
    int t = threadIdx.x;
    int s = (t < NB) ? btot[t] : 0;
    sums[t] = s;
    __syncthreads();
    for (int d = 1; d < 512; d <<= 1) {
        int v = (t >= d) ? sums[t - d] : 0;
        __syncthreads();
        sums[t] += v;
        __syncthreads();
    }
    if (t < NB) {
        bbase[t] = sums[t] - s;
        if (t == NB - 1) bbase[NB] = sums[t]; // == E
    }
}

// ------- P3: scatter int2{rowlocal:8|col:16, ea} into bucket runs (LDS cursors) -------
__global__ __launch_bounds__(1024) void k_p3_part(const int* __restrict__ row,
                                                  const int* __restrict__ col,
                                                  const float* __restrict__ ea,
                                                  const int* __restrict__ blkhist,
                                                  const int* __restrict__ bbase,
                                                  int2* __restrict__ pea) {
    __shared__ int cur[NB];
    int tid = threadIdx.x, blk = blockIdx.x;
    for (int i = tid; i < NB; i += 1024)
        cur[i] = bbase[i] + blkhist[i * NBLK + blk];
    __syncthreads();
    int s = blk * EPB, e = s + EPB; if (e > N_EDGES) e = N_EDGES;
    for (int i = s + tid; i < e; i += 1024) {
        int r = row[i], c = col[i];
        float a = ea[i];
        int slot = atomicAdd(&cur[r >> 7], 1);
        pea[slot] = make_int2(((r & (RPB - 1)) << 16) | c, __float_as_int(a));
    }
}

// ------- P4a: per-bucket counts + ea_sum + local scan -> offs, pxe -------
__global__ __launch_bounds__(512) void k_p4a(const int2* __restrict__ pea,
                                             const int* __restrict__ bbase,
                                             const float* __restrict__ x,
                                             int* __restrict__ offs,
                                             float* __restrict__ ea_sum,
                                             float2* __restrict__ pxe) {
    __shared__ int   cnt[RPB];
    __shared__ float eas[RPB];
    __shared__ int   scan_s[RPB];
    int tid = threadIdx.x, b = blockIdx.x;
    if (tid < RPB) { cnt[tid] = 0; eas[tid] = 0.f; }
    __syncthreads();
    int s = bbase[b], e = bbase[b + 1];
    for (int i = s + tid; i < e; i += 512) {
        int2 p = pea[i];
        int lr = ((uint32)p.x) >> 16;
        atomicAdd(&cnt[lr], 1);
        atomicAdd(&eas[lr], __int_as_float(p.y));
    }
    __syncthreads();
    if (tid < RPB) scan_s[tid] = cnt[tid];
    __syncthreads();
    for (int d = 1; d < RPB; d <<= 1) {
        int v = 0;
        if (tid < RPB && tid >= d) v = scan_s[tid - d];
        __syncthreads();
        if (tid < RPB) scan_s[tid] += v;
        __syncthreads();
    }
    int nbase = b * RPB;
    if (tid < RPB) {
        int excl = scan_s[tid] - cnt[tid];
        int n = nbase + tid;
        if (n < N_NODES) {
            offs[n] = s + excl;
            ea_sum[n] = eas[tid];
            pxe[n] = make_float2(x[n], eas[tid]);
        }
    }
    if (b == NB - 1 && tid == 0) offs[N_NODES] = e;
}

// ------- P4b: scatter csr + CSR-ordered payload pxec[slot] = pxe[col] -------
__global__ __launch_bounds__(512) void k_p4b(const int2* __restrict__ pea,
                                             const int* __restrict__ bbase,
                                             const int* __restrict__ offs,
                                             const float2* __restrict__ pxe,
                                             int* __restrict__ csr,
                                             float2* __restrict__ pxec) {
    __shared__ int cur[RPB];
    int tid = threadIdx.x, b = blockIdx.x;
    int nbase = b * RPB;
    if (tid < RPB) cur[tid] = (nbase + tid < N_NODES) ? offs[nbase + tid] : 0;
    __syncthreads();
    int s = bbase[b], e = bbase[b + 1];
    for (int i = s + tid; i < e; i += 512) {
        int2 p = pea[i];
        int c = p.x & 0xFFFF;
        int slot = atomicAdd(&cur[((uint32)p.x) >> 16], 1);
        csr[slot] = c;
        pxec[slot] = pxe[c];   // 400 KB table, L2-resident
    }
}

// ------- prep: pack W2 (x3) + W7 into MFMA B-fragment order (bf16); v3 = W3@relu(W4) -------
__global__ __launch_bounds__(256) void k_prep(const float* __restrict__ W2,
                                              const float* __restrict__ W7,
                                              const float* __restrict__ W3,
                                              const float* __restrict__ W4,
                                              ushort* __restrict__ wpack,  // 4 layers x 16384
                                              float* __restrict__ v3) {
    int idx = blockIdx.x * 256 + threadIdx.x;
    if (idx < 4 * 16384) {
        int m = idx >> 14, f = idx & 16383;
        int j = f & 7, lane = (f >> 3) & 63, kk = (f >> 9) & 3, t = (f >> 11) & 7;
        int hp = t * 16 + (lane & 15);
        int k  = kk * 32 + ((lane >> 4) & 3) * 8 + j;
        const float* src = (m < 3) ? (W2 + m * HID * HID) : W7;
        wpack[idx] = (ushort)bf16r(src[hp * HID + k]);
    }
    if (idx < 3 * HID) {
        int l = idx / HID, hp = idx % HID;
        float acc = 0.f;
        for (int h = 0; h < HID; h++)
            acc += W3[l * HID * HID + hp * HID + h] * fmaxf(W4[l * HID + h], 0.f);
        v3[idx] = acc;
    }
}

// ------- hop-1 gather by recompute, streaming CSR-ordered payload (no indirection) -------
__global__ __launch_bounds__(256) void k_gather1(const float2* __restrict__ pxec,
                                                 const int* __restrict__ offs,
                                                 const float* __restrict__ w1,
                                                 const float* __restrict__ v3,
                                                 uint32* __restrict__ agg) {
    int node = (blockIdx.x * 256 + threadIdx.x) >> 6;
    int lane = threadIdx.x & 63;
    if (node >= N_NODES) return;
    f32x2 w1v = {w1[2 * lane], w1[2 * lane + 1]};
    f32x2 v3v = {v3[2 * lane], v3[2 * lane + 1]};
    const f32x2 zero = {0.f, 0.f};
    int s = offs[node], e = offs[node + 1];
    f32x2 acc[4] = {zero, zero, zero, zero};
    int j = s;
    for (; j + 8 <= e; j += 8) {
        float2 p[8];
#pragma unroll
        for (int u = 0; u < 8; u++) p[u] = pxec[j + u];   // broadcast, contiguous
#pragma unroll
        for (int u = 0; u < 8; u++) {
            f32x2 px = {p[u].x, p[u].x};
            f32x2 pe = {p[u].y, p[u].y};
            f32x2 r = __builtin_elementwise_fma(px, w1v, pe * v3v);
            acc[u & 3] += __builtin_elementwise_max(r, zero);
        }
    }
    for (; j < e; j++) {
        float2 p = pxec[j];
        f32x2 px = {p.x, p.x};
        f32x2 pe = {p.y, p.y};
        f32x2 r = __builtin_elementwise_fma(px, w1v, pe * v3v);
        acc[0] += __builtin_elementwise_max(r, zero);
    }
    f32x2 rs = (acc[0] + acc[1]) + (acc[2] + acc[3]);
    agg[(size_t)node * 64 + lane] = pack_bf16(rs.x, rs.y);
}

// ------- hop-2 gather over fp8 emb rows (128 B): coalesced csr + shfl; x64 rescale -------
__global__ __launch_bounds__(256) void k_gather(const uchar* __restrict__ emb8,
                                                const int* __restrict__ offs,
                                                const int* __restrict__ csr,
                                                uint32* __restrict__ agg) {
    int node = (blockIdx.x * 256 + threadIdx.x) >> 6;
    int lane = threadIdx.x & 63;
    if (node >= N_NODES) return;
    int s = offs[node], e = offs[node + 1];
    float ax[8] = {0.f}, ay[8] = {0.f};
    for (int base = s; base < e; base += 64) {
        int idx = base + lane;
        int cv = (idx < e) ? csr[idx] : 0;     // one coalesced load per 64 edges
        int cnt = e - base; if (cnt > 64) cnt = 64;
        int j = 0;
        for (; j + 8 <= cnt; j += 8) {
            int h16[8];
#pragma unroll
            for (int u = 0; u < 8; u++) {
                int c = __shfl(cv, j + u);
                h16[u] = *(const ushort*)(emb8 + (size_t)c * 128 + 2 * lane);
            }
#pragma unroll
            for (int u = 0; u < 8; u++) {
                f32x2 d = __builtin_amdgcn_cvt_pk_f32_fp8(h16[u], false);
                ax[u] += d.x; ay[u] += d.y;
            }
        }
        for (; j < cnt; j++) {
            int c = __shfl(cv, j);
            int h = *(const ushort*)(emb8 + (size_t)c * 128 + 2 * lane);
            f32x2 d = __builtin_amdgcn_cvt_pk_f32_fp8(h, false);
            ax[0] += d.x; ay[0] += d.y;
        }
    }
    float rx = (((ax[0] + ax[1]) + (ax[2] + ax[3])) + ((ax[4] + ax[5]) + (ax[6] + ax[7]))) * 64.f;
    float ry = (((ay[0] + ay[1]) + (ay[2] + ay[3])) + ((ay[4] + ay[5]) + (ay[6] + ay[7]))) * 64.f;
    agg[(size_t)node * 64 + lane] = pack_bf16(rx, ry);
}

#define LROW 136  // padded LDS row, bf16 elems

// ------- MFMA GEMM hop: emb = relu(agg @ W2T + x*w1 + ea*v3) -------
// !LAST: emit fp8 emb (scale 2^-6, row 128 B).  LAST: emit bf16 emb + fused W7-head.
template <bool LAST>
__global__ __launch_bounds__(256) void k_gemm(const uint32* __restrict__ agg,   // bf16 [N][64u32]
                                              const ushort* __restrict__ w2p,   // B-frag packed
                                              const float* __restrict__ w1l,
                                              const float* __restrict__ v3l,
                                              const float* __restrict__ x,
                                              const float* __restrict__ ea_sum,
                                              uint32* __restrict__ embOut,      // bf16 (LAST)
                                              uchar* __restrict__ emb8Out,      // fp8 (!LAST)
                                              const ushort* __restrict__ w7p,
                                              const float* __restrict__ W5,
                                              float* __restrict__ outp) {
    __shared__ ushort tile[64 * LROW]; // 17408 B
    int tid = threadIdx.x;
    int tbase = blockIdx.x * 64;
    {
        const uint2* src = (const uint2*)(agg + (size_t)tbase * 64);
        int vn = N_NODES - tbase; if (vn > 64) vn = 64;
        int lim = vn * 32;
        for (int i = tid; i < 64 * 32; i += 256) {
            uint2 u = (i < lim) ? src[i] : make_uint2(0u, 0u);
            int r = i >> 5, c4 = (i & 31) * 4;
            *(uint2*)&tile[r * LROW + c4] = u;
        }
    }
    __syncthreads();
    int wv = tid >> 6, lane = tid & 63;
    int n0 = lane & 15, quad = lane >> 4;
    int arow = wv * 16 + n0;
    bf16x8 a0 = *(const bf16x8*)&tile[arow * LROW + 0 * 32 + quad * 8];
    bf16x8 a1 = *(const bf16x8*)&tile[arow * LROW + 1 * 32 + quad * 8];
    bf16x8 a2 = *(const bf16x8*)&tile[arow * LROW + 2 * 32 + quad * 8];
    bf16x8 a3 = *(const bf16x8*)&tile[arow * LROW + 3 * 32 + quad * 8];
    const bf16x8* wb = (const bf16x8*)w2p;
    f32x4 acc[8];
#pragma unroll
    for (int t = 0; t < 8; t++) {
        f32x4 c = {0.f, 0.f, 0.f, 0.f};
        c = __builtin_amdgcn_mfma_f32_16x16x32_bf16(a0, wb[(t * 4 + 0) * 64 + lane], c, 0, 0, 0);
        c = __builtin_amdgcn_mfma_f32_16x16x32_bf16(a1, wb[(t * 4 + 1) * 64 + lane], c, 0, 0, 0);
        c = __builtin_amdgcn_mfma_f32_16x16x32_bf16(a2, wb[(t * 4 + 2) * 64 + lane], c, 0, 0, 0);
        c = __builtin_amdgcn_mfma_f32_16x16x32_bf16(a3, wb[(t * 4 + 3) * 64 + lane], c, 0, 0, 0);
        acc[t] = c;
    }
    float xs[4], es[4];
#pragma unroll
    for (int r = 0; r < 4; r++) {
        int n = tbase + wv * 16 + quad * 4 + r;
        xs[r] = (n < N_NODES) ? x[n] : 0.f;
        es[r] = (n < N_NODES) ? ea_sum[n] : 0.f;
    }
    if (!LAST) {
        // epilogue: fp8 output, scale 2^-6 (exact pow2; rescaled x64 in k_gather)
        uchar* stile = (uchar*)tile;   // rows stride 136 B; wave-private rows
#pragma unroll
        for (int t = 0; t < 8; t++) {
            int hp = t * 16 + n0;
            float w1v = w1l[hp], v3v = v3l[hp];
#pragma unroll
            for (int r = 0; r < 4; r++) {
                float v = fmaxf(acc[t][r] + xs[r] * w1v + es[r] * v3v, 0.f) * 0.015625f;
                int enc = __builtin_amdgcn_cvt_pk_fp8_f32(v, v, 0, false);
                stile[(wv * 16 + quad * 4 + r) * 136 + hp] = (uchar)(enc & 0xff);
            }
        }
        __syncthreads();
        int vn = N_NODES - tbase; if (vn > 64) vn = 64;
        for (int i = tid; i < 64 * 32; i += 256) {
            int r = i >> 5, c4 = (i & 31) * 4;
            if (r < vn) {
                uint32 u = *(const uint32*)&stile[r * 136 + c4];
                *(uint32*)(emb8Out + (size_t)(tbase + r) * 128 + c4) = u;
            }
        }
    } else {
        // epilogue: bf16 output back through LDS + fused W7 head
#pragma unroll
        for (int t = 0; t < 8; t++) {
            int hp = t * 16 + n0;
            float w1v = w1l[hp], v3v = v3l[hp];
#pragma unroll
            for (int r = 0; r < 4; r++) {
                float v = fmaxf(acc[t][r] + xs[r] * w1v + es[r] * v3v, 0.f);
                tile[(wv * 16 + quad * 4 + r) * LROW + hp] = (ushort)bf16r(v);
            }
        }
        __syncthreads();
        {
            int vn = N_NODES - tbase; if (vn > 64) vn = 64;
            for (int i = tid; i < 64 * 32; i += 256) {
                int r = i >> 5, c4 = (i & 31) * 4;
                if (r < vn) {
                    uint2 u = *(const uint2*)&tile[r * LROW + c4];
                    *(uint2*)(embOut + (size_t)(tbase + r) * 64 + (size_t)(i & 31) * 2) = u;
                }
            }
        }
        bf16x8 b0 = *(const bf16x8*)&tile[arow * LROW + 0 * 32 + quad * 8];
        bf16x8 b1 = *(const bf16x8*)&tile[arow * LROW + 1 * 32 + quad * 8];
        bf16x8 b2 = *(const bf16x8*)&tile[arow * LROW + 2 * 32 + quad * 8];
        bf16x8 b3 = *(const bf16x8*)&tile[arow * LROW + 3 * 32 + quad * 8];
        const bf16x8* w7 = (const bf16x8*)w7p;
        float p[4] = {0.f, 0.f, 0.f, 0.f};
#pragma unroll
        for (int t = 0; t < 8; t++) {
            f32x4 c = {0.f, 0.f, 0.f, 0.f};
            c = __builtin_amdgcn_mfma_f32_16x16x32_bf16(b0, w7[(t * 4 + 0) * 64 + lane], c, 0, 0, 0);
            c = __builtin_amdgcn_mfma_f32_16x16x32_bf16(b1, w7[(t * 4 + 1) * 64 + lane], c, 0, 0, 0);
            c = __builtin_amdgcn_mfma_f32_16x16x32_bf16(b2, w7[(t * 4 + 2) * 64 + lane], c, 0, 0, 0);
            c = __builtin_amdgcn_mfma_f32_16x16x32_bf16(b3, w7[(t * 4 + 3) * 64 + lane], c, 0, 0, 0);
            float w5v = W5[128 + t * 16 + n0];
#pragma unroll
            for (int r = 0; r < 4; r++) p[r] += fmaxf(c[r], 0.f) * w5v;
        }
#pragma unroll
        for (int r = 0; r < 4; r++) {
            float v = p[r];
            v += __shfl_xor(v, 1);
            v += __shfl_xor(v, 2);
            v += __shfl_xor(v, 4);
            v += __shfl_xor(v, 8);
            int n = tbase + wv * 16 + quad * 4 + r;
            if (n0 == 0 && n < N_NODES) outp[n] = v;
        }
    }
}

// ------- pooling: 16 graphs x 16 chunks, branch-free, 4-node ILP -------
__global__ __launch_bounds__(256) void k_pool2(const uint32* __restrict__ emb,
                                               const int* __restrict__ gstart,
                                               float* __restrict__ pooled) {
    __shared__ float2 red[4][64];
    int bid = blockIdx.x;
    int g = bid >> 4, chunk = bid & 15;
    int gs = gstart[g], ge = gstart[g + 1];
    int len = ge - gs;
    int cs = gs + (int)(((long long)len * chunk) >> 4);
    int ce = gs + (int)(((long long)len * (chunk + 1)) >> 4);
    int sub = threadIdx.x >> 6, lane = threadIdx.x & 63;
    float ax = 0.f, ay = 0.f;
    for (int n = cs + sub; n < ce; n += 4) {
        uint32 u = emb[(size_t)n * 64 + lane];
        ax += bf_lo(u); ay += bf_hi(u);
    }
    red[sub][lane] = make_float2(ax, ay);
    __syncthreads();
    if (sub == 0) {
        float2 r0 = red[0][lane], r1 = red[1][lane], r2 = red[2][lane], r3 = red[3][lane];
        atomicAdd(&pooled[g * HID + 2 * lane],     (r0.x + r1.x) + (r2.x + r3.x));
        atomicAdd(&pooled[g * HID + 2 * lane + 1], (r0.y + r1.y) + (r2.y + r3.y));
    }
}

// ---------------- per-graph scalar: s_g = relu(pooled@W6T) . W5[:128] ----------------
__global__ __launch_bounds__(128) void k_graph(const float* __restrict__ pooled,
                                               const float* __restrict__ W6,
                                               const float* __restrict__ W5,
                                               float* __restrict__ s_g) {
    int g = blockIdx.x, hp = threadIdx.x;
    float acc = 0.f;
    for (int h = 0; h < HID; h++) acc += pooled[g * HID + h] * W6[hp * HID + h];
    float v = fmaxf(acc, 0.f) * W5[hp];
    __shared__ float red[HID];
    red[hp] = v;
    __syncthreads();
    for (int d = 64; d > 0; d >>= 1) {
        if (hp < d) red[hp] += red[hp + d];
        __syncthreads();
    }
    if (hp == 0) s_g[g] = red[0];
}

// ---------------- final add: out[n] += s_g[batch[n]] + b5 ----------------
__global__ __launch_bounds__(256) void k_addsg(float* __restrict__ out,
                                               const int* __restrict__ batch,
                                               const float* __restrict__ s_g,
                                               const float* __restrict__ b5) {
    int n = blockIdx.x * 256 + threadIdx.x;
    if (n < N_NODES) out[n] += s_g[batch[n]] + b5[0];
}

extern "C" void kernel_launch(void* const* d_in, const int* in_sizes, int n_in,
                              void* d_out, int out_size, void* d_ws, size_t ws_size,
                              hipStream_t stream) {
    (void)in_sizes; (void)n_in; (void)out_size; (void)ws_size;
    const float* x    = (const float*)d_in[0];
    const int*   ei   = (const int*)d_in[1];   // [2,E] flat: row then col
    const float* ea   = (const float*)d_in[2];
    const int*   bat  = (const int*)d_in[3];
    const float* W1   = (const float*)d_in[4]; // [3,128,1]
    const float* W2   = (const float*)d_in[5]; // [3,128,128]
    const float* W3   = (const float*)d_in[6];
    const float* W4   = (const float*)d_in[7]; // [3,128,1]
    const float* W5   = (const float*)d_in[8]; // [1,256]
    const float* b5   = (const float*)d_in[9];
    const float* W6   = (const float*)d_in[10];
    const float* W7   = (const float*)d_in[11];
    float* out = (float*)d_out;

    const int* row = ei;
    const int* col = ei + N_EDGES;

    // workspace layout (4B elems)
    float* wsf = (float*)d_ws;
    int*   wsi = (int*)d_ws;
    size_t o = 0;
    float* pooled = wsf + o; o += NGRAPH * HID;     // zeroed (atomic targets)
    float* s_g    = wsf + o; o += NGRAPH;           // zeroed
    size_t ztot = o;
    int*   offs   = wsi + o; o += N_NODES + 1;
    float* ea_sum = wsf + o; o += N_NODES;
    int*   gstart = wsi + o; o += NGRAPH + 1;
    int*   btot   = wsi + o; o += NB;
    int*   bbase  = wsi + o; o += NB + 1;
    float* v3     = wsf + o; o += 3 * HID;
    int*   blkh   = wsi + o; o += NB * NBLK;
    o = (o + 1) & ~(size_t)1;
    float2* pxe   = (float2*)(wsi + o); o += 2 * (size_t)N_NODES;
    o = (o + 3) & ~(size_t)3;
    ushort* wpack = (ushort*)(wsi + o); o += 4 * 16384 / 2;
    int*    csr   = wsi + o; o += N_EDGES;
    o = (o + 1) & ~(size_t)1;
    int2*   pea   = (int2*)(wsi + o); o += 2 * (size_t)N_EDGES;
    float2* pxec  = (float2*)(wsi + o); o += 2 * (size_t)N_EDGES;
    o = (o + 1) & ~(size_t)1;
    uint32* embA  = (uint32*)(wsi + o); o += (size_t)N_NODES * 64;  // bf16 [N][128]
    uchar*  emb8  = (uchar*)(wsi + o);  o += (size_t)N_NODES * 32;  // fp8  [N][128]
    uint32* aggB  = (uint32*)(wsi + o); o += (size_t)N_NODES * 64;  // bf16 [N][128]

    const ushort* w2p1 = wpack + 1 * 16384;
    const ushort* w2p2 = wpack + 2 * 16384;
    const ushort* w7p  = wpack + 3 * 16384;

    // 0) zero atomic accumulators + graph boundaries (fused)
    k_init<<<(int)((ztot + 255) / 256), 256, 0, stream>>>((float*)d_ws, (int)ztot, bat, gstart);
    // 1) atomic-free CSR build + CSR-ordered hop-1 payload
    k_p1_hist<<<NBLK, 1024, 0, stream>>>(row, blkh);
    k_p2a<<<NB, NBLK, 0, stream>>>(blkh, btot);
    k_p2b<<<1, 512, 0, stream>>>(btot, bbase);
    k_p3_part<<<NBLK, 1024, 0, stream>>>(row, col, ea, blkh, bbase, pea);
    k_p4a<<<NB, 512, 0, stream>>>(pea, bbase, x, offs, ea_sum, pxe);
    k_p4b<<<NB, 512, 0, stream>>>(pea, bbase, offs, pxe, csr, pxec);
    // 2) weight prep: MFMA B-frag packs + v3
    k_prep<<<(4 * 16384 + 255) / 256, 256, 0, stream>>>(W2, W7, W3, W4, (ushort*)wpack, v3);
    // 3) hop 1: streaming recompute-gather -> aggB ; MFMA gemm -> emb8 (fp8, scale 2^-6)
    k_gather1<<<(N_NODES * 64 + 255) / 256, 256, 0, stream>>>(pxec, offs, W1, v3, aggB);
    k_gemm<false><<<(N_NODES + 63) / 64, 256, 0, stream>>>(
        aggB, w2p1, W1 + 1 * HID, v3 + 1 * HID, x, ea_sum, nullptr, emb8, nullptr, nullptr, nullptr);
    // 4) hop 2: gather emb8 -> aggB ; MFMA gemm + W7 head -> embA, out partial
    k_gather<<<(N_NODES * 64 + 255) / 256, 256, 0, stream>>>(emb8, offs, csr, aggB);
    k_gemm<true><<<(N_NODES + 63) / 64, 256, 0, stream>>>(
        aggB, w2p2, W1 + 2 * HID, v3 + 2 * HID, x, ea_sum, embA, nullptr, w7p, W5, out);
    // 5) graph pooling (parallel, branch-free)
    k_pool2<<<NGRAPH * 16, 256, 0, stream>>>(embA, gstart, pooled);
    // 6) per-graph scalars
    k_graph<<<NGRAPH, 128, 0, stream>>>(pooled, W6, W5, s_g);
    // 7) add graph term + bias
    k_addsg<<<(N_NODES + 255) / 256, 256, 0, stream>>>(out, bat, s_g, b5);
}